// Round 8
// baseline (232.373 us; speedup 1.0000x reference)
//
#include <hip/hip_runtime.h>
#include <hip/hip_bf16.h>
#include <stdint.h>

#define IN_F 128
#define EDGE_F 6
#define TILE_E 4096      // per-block sort tile (block-local)
#define NBIN_PAD 256     // coarse bins = dst>>8 (n_nodes <= 65536; N=50000 -> 196 used)
#define BCAP 8192        // padded records per bucket (~60 sigma margin)
#define IDXN 8192        // fine_rank LDS index capacity
#define CAST_B 400       // dedicated cast blocks riding in the K1 grid

using bf16x8 = __attribute__((ext_vector_type(8))) short;  // 8 bf16 = 4 VGPRs
using f32x4  = __attribute__((ext_vector_type(4))) float;

__device__ __forceinline__ float bf2f(unsigned short u) {
    return __uint_as_float(((unsigned int)u) << 16);
}
__device__ __forceinline__ unsigned short f2bfbits(float f) {
    __hip_bfloat16 h = __float2bfloat16(f);  // RNE
    return *reinterpret_cast<unsigned short*>(&h);
}
__device__ __forceinline__ unsigned int packbf(float a, float b) {
    return ((unsigned int)f2bfbits(b) << 16) | (unsigned int)f2bfbits(a);
}

// ---- K1: block-LOCAL counting sort + inline pack + QUARTER-MAJOR nf cast ----
// Sort blocks: LDS hist of 256 coarse bins, local scan, scatter packed records
// bin-grouped within their own 64KB segment. No cross-block coordination.
// Cast blocks now write nfb QUARTER-MAJOR: nfbq[q][(N+1)][32 feats] -- four
// 3.2MB tables, each small enough to be L2-resident per XCD during the
// aggregate's per-quarter pass (the whole point of this round).
__global__ __launch_bounds__(256) void sort_pack_cast(
        const int* __restrict__ eidx, const float* __restrict__ ef,
        uint4* __restrict__ rec_c, unsigned short* __restrict__ pmat,
        unsigned short* __restrict__ lmat,
        int n_edges, int nblk_e, int n_nodes,
        const float* __restrict__ nf, unsigned short* __restrict__ nfbq,
        const float* __restrict__ W, const float* __restrict__ b,
        const float* __restrict__ We, const float* __restrict__ be,
        unsigned short* __restrict__ Wpack, float* __restrict__ W2pack) {
    const int tid = threadIdx.x;
    const int blk = blockIdx.x;
    const size_t qstr = (size_t)(n_nodes + 1) * 32;   // ushorts per quarter table
    __shared__ unsigned int qxs[TILE_E];   // 16 KB: packed src|dst<<16
    __shared__ int hist[NBIN_PAD];
    __shared__ int cur[NBIN_PAD];

    if (blk < nblk_e) {
        hist[tid] = 0;
        __syncthreads();
        const int e0 = blk * TILE_E;
        const int lim = min(TILE_E, n_edges - e0);
        // pass A: stage qx in LDS + LDS hist (eidx read ONCE)
        for (int i = tid; i < lim; i += 256) {
            const int2 pr = reinterpret_cast<const int2*>(eidx)[e0 + i];  // (src,dst)
            const unsigned int q = (unsigned int)pr.x | ((unsigned int)pr.y << 16);
            qxs[i] = q;
            atomicAdd(&hist[q >> 24], 1);          // q>>24 == dst>>8
        }
        __syncthreads();
        const int own = hist[tid];
        for (int off = 1; off < 256; off <<= 1) {  // inclusive scan of bin counts
            int t2 = (tid >= off) ? hist[tid - off] : 0;
            __syncthreads();
            hist[tid] += t2;
            __syncthreads();
        }
        const int excl = hist[tid] - own;          // local bin offset
        pmat[(size_t)blk * NBIN_PAD + tid] = (unsigned short)own;
        lmat[(size_t)blk * NBIN_PAD + tid] = (unsigned short)excl;
        cur[tid] = excl;
        __syncthreads();
        // pass B: read ef (coalesced), pack 16B record, scatter into OWN segment
        uint4* seg = rec_c + (size_t)blk * TILE_E;
        for (int i = tid; i < lim; i += 256) {
            const unsigned int q = qxs[i];
            const float2* efs = reinterpret_cast<const float2*>(ef + (size_t)(e0 + i) * EDGE_F);
            const float2 f0 = efs[0], f1 = efs[1], f2 = efs[2];
            uint4 r;
            r.x = q;
            r.y = packbf(f0.x, f0.y);
            r.z = packbf(f1.x, f1.y);
            r.w = packbf(f2.x, f2.y);
            const int pos = atomicAdd(&cur[q >> 24], 1);
            seg[pos] = r;                          // 64KB window, bin-grouped
        }
    } else if (blk == nblk_e) {
        // Wpack: idx=((kb*8+ft)*64+lane)*8+j -> bf16(W[kb*32+(lane>>4)*8+j][ft*16+(lane&15)])
        for (int idx = tid; idx < 16384; idx += 256) {
            int j = idx & 7, lane = (idx >> 3) & 63, ft = (idx >> 9) & 7, kb = idx >> 12;
            int k = kb * 32 + (lane >> 4) * 8 + j;
            int f = ft * 16 + (lane & 15);
            Wpack[idx] = f2bfbits(W[k * 128 + f]);
        }
        for (int idx = tid; idx < 1024; idx += 256) {
            int j = idx >> 7, f = idx & 127;
            float w = 0.f;
            if (j < 6)       w = We[j * 128 + f];
            else if (j == 6) w = b[f] + be[f];
            W2pack[idx] = w;
        }
        // dummy node row (index n_nodes) in EACH quarter table: zero 64B.
        if (tid < 16) {
            const int q = tid >> 2, sub = tid & 3;
            uint4 z; z.x = z.y = z.z = z.w = 0u;
            *reinterpret_cast<uint4*>(nfbq + (size_t)q * qstr +
                                      (size_t)n_nodes * 32 + sub * 8) = z;
        }
    } else {
        // cast: nf fp32 -> bf16, quarter-major. Unit = 16B out (8 feats).
        // Order (q, node, sub): writes perfectly sequential per quarter.
        const int cb = blk - nblk_e - 1;
        const int ncb = gridDim.x - nblk_e - 1;
        const int per_q = n_nodes * 4;
        const int total = n_nodes * 16;
        for (int i = cb * 256 + tid; i < total; i += ncb * 256) {
            const int q = i / per_q;
            const int rem = i - q * per_q;
            const int node = rem >> 2, sub = rem & 3;
            const float4 lo = *reinterpret_cast<const float4*>(
                nf + (size_t)node * IN_F + q * 32 + sub * 8);
            const float4 hi = *reinterpret_cast<const float4*>(
                nf + (size_t)node * IN_F + q * 32 + sub * 8 + 4);
            uint4 o;
            o.x = packbf(lo.x, lo.y); o.y = packbf(lo.z, lo.w);
            o.z = packbf(hi.x, hi.y); o.w = packbf(hi.z, hi.w);
            *reinterpret_cast<uint4*>(nfbq + (size_t)q * qstr +
                                      (size_t)node * 32 + sub * 8) = o;
        }
    }
}

// ---- K2: FLAT-PARALLEL bucket assembly + fine sort -> PADDED rec + srcp + pr2 ----
// 512 threads/bucket; run-length scan + 8-step binary search resolves every
// record index; 4-deep independent batches both passes; indices cached in
// 32KB LDS between passes (R7: this form won +17us over the serial-run walk).
// NEW: also writes srcp[] (ranked src as ushort, 2B/edge) so the aggregate's
// quarter passes 1-3 never touch the 16B records. Pads (src=n_nodes -> zero
// rows) keep every dst run a multiple of 8.
__global__ __launch_bounds__(512) void fine_rank(
        const uint4* __restrict__ rec_c, const unsigned short* __restrict__ pmat,
        const unsigned short* __restrict__ lmat,
        uint4* __restrict__ rec, unsigned short* __restrict__ srcp,
        int2* __restrict__ pr2, int n_nodes, int nblk_e) {
    const int tid = threadIdx.x;
    const int c = blockIdx.x;
    __shared__ int rstart[NBIN_PAD + 1];
    __shared__ int rbaseg[NBIN_PAD];
    __shared__ int fcnt[256];
    __shared__ int fpos[256];
    __shared__ int idxl[IDXN];             // 32 KB: linearized global record idx

    if (tid < 256) {
        const bool r = (tid < nblk_e);
        fcnt[tid] = r ? pmat[(size_t)tid * NBIN_PAD + c] : 0;
        rbaseg[tid] = tid * TILE_E + (r ? (int)lmat[(size_t)tid * NBIN_PAD + c] : 0);
    }
    __syncthreads();
    for (int off = 1; off < 256; off <<= 1) {
        int v = 0;
        if (tid < 256 && tid >= off) v = fcnt[tid - off];
        __syncthreads();
        if (tid < 256) fcnt[tid] += v;
        __syncthreads();
    }
    if (tid < 256) rstart[tid + 1] = fcnt[tid];
    if (tid == 0) rstart[0] = 0;
    __syncthreads();
    int sz = rstart[256];
    if (sz > IDXN) sz = IDXN;                   // guard only
    __syncthreads();
    if (tid < 256) fcnt[tid] = 0;
    __syncthreads();
    // pass 1: resolve indices (binary search), cache, dst histogram
    for (int base = 0; base < sz; base += 2048) {
        int ii[4], g[4];
        unsigned int qx[4];
#pragma unroll
        for (int u = 0; u < 4; ++u) ii[u] = base + u * 512 + tid;
#pragma unroll
        for (int u = 0; u < 4; ++u) {
            if (ii[u] < sz) {
                int lo = 0, hi = 255;
                while (lo < hi) {
                    const int mid = (lo + hi + 1) >> 1;
                    if (rstart[mid] <= ii[u]) lo = mid; else hi = mid - 1;
                }
                g[u] = rbaseg[lo] + (ii[u] - rstart[lo]);
                idxl[ii[u]] = g[u];
            }
        }
#pragma unroll
        for (int u = 0; u < 4; ++u)
            if (ii[u] < sz)
                qx[u] = reinterpret_cast<const unsigned int*>(rec_c)[(size_t)g[u] * 4];
#pragma unroll
        for (int u = 0; u < 4; ++u)
            if (ii[u] < sz) atomicAdd(&fcnt[(qx[u] >> 16) & 255], 1);
    }
    __syncthreads();
    int own = 0, ownp = 0, pexcl = 0;
    if (tid < 256) { own = fcnt[tid]; ownp = (own + 7) & ~7; fcnt[tid] = ownp; }
    __syncthreads();
    for (int off = 1; off < 256; off <<= 1) {
        int v = 0;
        if (tid < 256 && tid >= off) v = fcnt[tid - off];
        __syncthreads();
        if (tid < 256) fcnt[tid] += v;
        __syncthreads();
    }
    const size_t obase = (size_t)c * BCAP;
    if (tid < 256) {
        pexcl = fcnt[tid] - ownp;
        fpos[tid] = pexcl;
        const int n = c * 256 + tid;
        if (n < n_nodes) {
            int2 pr; pr.x = (int)(obase + pexcl); pr.y = own;
            pr2[n] = pr;
        }
    }
    __syncthreads();
    // pass 2: ranked scatter of records + srcp via cached indices
    for (int base = 0; base < sz; base += 2048) {
        int ii[4];
        uint4 q[4];
#pragma unroll
        for (int u = 0; u < 4; ++u) ii[u] = base + u * 512 + tid;
#pragma unroll
        for (int u = 0; u < 4; ++u)
            if (ii[u] < sz) q[u] = rec_c[idxl[ii[u]]];
#pragma unroll
        for (int u = 0; u < 4; ++u) {
            if (ii[u] < sz) {
                const int r = atomicAdd(&fpos[(q[u].x >> 16) & 255], 1);
                if (r < BCAP) {
                    rec[obase + r] = q[u];
                    srcp[obase + r] = (unsigned short)(q[u].x & 0xFFFFu);
                }
            }
        }
    }
    // pad fill: thread tid owns dst tid's <=7 dummy slots
    if (tid < 256) {
        uint4 dmy; dmy.x = (unsigned int)n_nodes; dmy.y = dmy.z = dmy.w = 0u;
        for (int j = own; j < ownp && pexcl + j < BCAP; ++j) {
            rec[obase + pexcl + j] = dmy;
            srcp[obase + pexcl + j] = (unsigned short)n_nodes;
        }
    }
}

// ---- K3: aggregate, QUARTER-SPLIT gather. 4 logical passes in one dispatch. ----
// pass = blockIdx.x / nbn. Each pass gathers 64B rows from ONE 3.2MB quarter
// table (fits a 4MB per-XCD L2; XCD round-robin makes passes near-sequential
// per XCD -> rows re-hit ~16x from L2 at ~34 TB/s instead of LLC at ~5).
// One wave = one dst; 8 lanes/edge: a full 8-edge batch is ONE coalesced
// dwordx2 gather (512B). Cross-edge fold = 3 shfl_xor at the end. Passes 1-3
// read only srcp (2B/edge); pass 0 reads rec for edge-feature sums + deg.
__global__ __launch_bounds__(256) void aggregate_bf16(
        const unsigned short* __restrict__ nfbq, const uint4* __restrict__ rec,
        const unsigned short* __restrict__ srcp, const int2* __restrict__ pr2,
        unsigned short* __restrict__ Sq, unsigned short* __restrict__ E8,
        int n_nodes, int nbn) {
    const int lane = threadIdx.x & 63;
    const int wv = __builtin_amdgcn_readfirstlane(threadIdx.x >> 6);
    const int pass = blockIdx.x / nbn;
    const int bi = blockIdx.x - pass * nbn;
    const int n = bi * 4 + wv;
    if (n >= n_nodes) return;
    const size_t qstr = (size_t)(n_nodes + 1) * 32;
    const unsigned short* tab = nfbq + (size_t)pass * qstr;
    const int2 pr = pr2[n];
    const int deg = pr.y;
    const int nb = (deg + 7) >> 3;             // all batches full (padded)
    const int es = lane >> 3;                  // edge slot 0..7
    const int fl = lane & 7;                   // feat slot: 4 feats (8B)
    float b0 = 0.f, b1 = 0.f, b2 = 0.f, b3 = 0.f;
    float e0 = 0.f, e1 = 0.f, e2 = 0.f, e3 = 0.f, e4 = 0.f, e5 = 0.f;
    int i = pr.x;
    for (int bb = 0; bb < nb; ++bb, i += 8) {
        const int s = srcp[i + es];            // 8 distinct addrs, one 16B fetch
        const uint2 u = *reinterpret_cast<const uint2*>(tab + (size_t)s * 32 + fl * 4);
        b0 += bf2f((unsigned short)u.x);
        b1 += bf2f((unsigned short)(u.x >> 16));
        b2 += bf2f((unsigned short)u.y);
        b3 += bf2f((unsigned short)(u.y >> 16));
        if (pass == 0) {                       // edge-feature sums (wave-uniform recs)
            uint4 q[8];
#pragma unroll
            for (int j = 0; j < 8; ++j) q[j] = rec[i + j];
#pragma unroll
            for (int j = 0; j < 8; ++j) {
                e0 += bf2f((unsigned short)q[j].y);
                e1 += bf2f((unsigned short)(q[j].y >> 16));
                e2 += bf2f((unsigned short)q[j].z);
                e3 += bf2f((unsigned short)(q[j].z >> 16));
                e4 += bf2f((unsigned short)q[j].w);
                e5 += bf2f((unsigned short)(q[j].w >> 16));
            }
        }
    }
    // fold the 8 edge-slot partials (feats)
    b0 += __shfl_xor(b0, 8, 64);  b1 += __shfl_xor(b1, 8, 64);
    b2 += __shfl_xor(b2, 8, 64);  b3 += __shfl_xor(b3, 8, 64);
    b0 += __shfl_xor(b0, 16, 64); b1 += __shfl_xor(b1, 16, 64);
    b2 += __shfl_xor(b2, 16, 64); b3 += __shfl_xor(b3, 16, 64);
    b0 += __shfl_xor(b0, 32, 64); b1 += __shfl_xor(b1, 32, 64);
    b2 += __shfl_xor(b2, 32, 64); b3 += __shfl_xor(b3, 32, 64);
    if (es == 0) {                             // lanes 0..7 write the 64B quarter-row
        uint2 o;
        o.x = packbf(b0, b1);
        o.y = packbf(b2, b3);
        *reinterpret_cast<uint2*>(Sq + (size_t)pass * n_nodes * 32 +
                                  (size_t)n * 32 + fl * 4) = o;
    }
    if (pass == 0 && lane == 0) {
        uint4 q;
        q.x = packbf(e0, e1);
        q.y = packbf(e2, e3);
        q.z = packbf(e4, e5);
        q.w = packbf((float)deg, 0.f);          // deg exact in bf16 (small)
        *reinterpret_cast<uint4*>(E8 + (size_t)n * 8) = q;
    }
}

// ---- K4: MFMA GEMM  out = relu( S @ W + E-term ), S quarter-major ----
// a[kb] comes from quarter table kb (exactly the MFMA K-block) -- still a
// 16B/lane fully-coalesced load. Coalesced LDS-staged epilogue (R7 win).
__global__ __launch_bounds__(256) void gemm_mfma(
        const unsigned short* __restrict__ Sq, const unsigned short* __restrict__ E8,
        const unsigned short* __restrict__ Wpack, const float* __restrict__ W2pack,
        float* __restrict__ out, int n_nodes) {
    __shared__ __align__(16) short Wl[16384];   // 32 KB: B-fragments, then out-stage
    __shared__ float W2l[1024];                 // 4 KB
    const int tid = threadIdx.x;
    for (int i = tid; i < 2048; i += 256)
        reinterpret_cast<uint4*>(Wl)[i] = reinterpret_cast<const uint4*>(Wpack)[i];
    for (int i = tid; i < 1024; i += 256) W2l[i] = W2pack[i];

    const int wv = tid >> 6, lane = tid & 63;
    const int m = lane & 15, quad = lane >> 4;
    const int n0 = blockIdx.x * 64 + wv * 16;

    const int arow = min(n0 + m, n_nodes - 1);
    bf16x8 a[4];
#pragma unroll
    for (int kb = 0; kb < 4; ++kb)
        a[kb] = *reinterpret_cast<const bf16x8*>(
            Sq + (size_t)kb * n_nodes * 32 + (size_t)arow * 32 + quad * 8);

    __syncthreads();

    f32x4 acc[8];
#pragma unroll
    for (int ft = 0; ft < 8; ++ft) acc[ft] = (f32x4){0.f, 0.f, 0.f, 0.f};

#pragma unroll
    for (int kb = 0; kb < 4; ++kb) {
#pragma unroll
        for (int ft = 0; ft < 8; ++ft) {
            const bf16x8 bfrag =
                reinterpret_cast<const bf16x8*>(Wl)[(kb * 8 + ft) * 64 + lane];
            acc[ft] = __builtin_amdgcn_mfma_f32_16x16x32_bf16(a[kb], bfrag, acc[ft], 0, 0, 0);
        }
    }

    // Epilogue. C/D layout: col=lane&15, row=quad*4+reg.
    float e[4][7];
#pragma unroll
    for (int r = 0; r < 4; ++r) {
        const int n = min(n0 + quad * 4 + r, n_nodes - 1);
        const uint4 q = *reinterpret_cast<const uint4*>(E8 + (size_t)n * 8);
        e[r][0] = bf2f((unsigned short)q.x); e[r][1] = bf2f((unsigned short)(q.x >> 16));
        e[r][2] = bf2f((unsigned short)q.y); e[r][3] = bf2f((unsigned short)(q.y >> 16));
        e[r][4] = bf2f((unsigned short)q.z); e[r][5] = bf2f((unsigned short)(q.z >> 16));
        e[r][6] = bf2f((unsigned short)q.w);  // deg
    }
    __syncthreads();                            // Wl B-fragment reads complete
    float* So = reinterpret_cast<float*>(Wl);   // 64 rows x 128 f32 = 32 KB
#pragma unroll
    for (int ft = 0; ft < 8; ++ft) {
        const int f = ft * 16 + m;
        float w2[7];
#pragma unroll
        for (int j = 0; j < 7; ++j) w2[j] = W2l[j * 128 + f];
#pragma unroll
        for (int r = 0; r < 4; ++r) {
            float v = acc[ft][r];
#pragma unroll
            for (int j = 0; j < 7; ++j) v += e[r][j] * w2[j];
            So[(wv * 16 + quad * 4 + r) * 128 + f] = fmaxf(v, 0.f);
        }
    }
    __syncthreads();
    const size_t nb0 = (size_t)blockIdx.x * 64;
    for (int i = tid; i < 2048; i += 256) {     // 16B/lane, fully coalesced
        const int row = i >> 5;
        if (nb0 + row < (size_t)n_nodes)
            reinterpret_cast<uint4*>(out)[(nb0 + row) * 32 + (i & 31)] =
                reinterpret_cast<const uint4*>(So)[i];
    }
}

extern "C" void kernel_launch(void* const* d_in, const int* in_sizes, int n_in,
                              void* d_out, int out_size, void* d_ws, size_t ws_size,
                              hipStream_t stream) {
    const float* nf = (const float*)d_in[0];  // fp32 (N,128)
    const int* eidx = (const int*)d_in[1];    // int32 (E,2)
    const float* ef = (const float*)d_in[2];  // fp32 (E,6)
    const float* W  = (const float*)d_in[3];  // fp32 (128,128)
    const float* b  = (const float*)d_in[4];  // fp32 (128,)
    const float* We = (const float*)d_in[5];  // fp32 (6,128)
    const float* be = (const float*)d_in[6];  // fp32 (128,)
    float* out = (float*)d_out;               // fp32 (N,128)

    const int n_nodes = in_sizes[0] / IN_F;
    const int n_edges = in_sizes[1] / 2;

    const int nblk_e = (n_edges + TILE_E - 1) / TILE_E;   // 196 sort blocks (<=256 req'd)
    const int nbin = (n_nodes + 255) >> 8;                // 196 fine buckets
    const int nbn = (n_nodes + 3) / 4;                    // aggregate blocks per pass

    // ws (~70 MB), all 16B-aligned section sizes:
    // rec (nbin*BCAP uint4) | rec_c (nblk_e*TILE_E uint4) | E8 | Wpack
    //   | Sq (4*N*32 ush, quarter-major) | nfbq (4*(N+1)*32 ush) | srcp
    //   | pmat | lmat | W2pack | pr2
    uint4* rec   = (uint4*)d_ws;
    uint4* rec_c = rec + (size_t)nbin * BCAP;
    unsigned short* E8 = (unsigned short*)(rec_c + (size_t)nblk_e * TILE_E);
    unsigned short* Wpack = E8 + (size_t)n_nodes * 8;
    unsigned short* Sq = Wpack + 16384;
    unsigned short* nfbq = Sq + (size_t)4 * n_nodes * 32;
    unsigned short* srcp = nfbq + (size_t)4 * (n_nodes + 1) * 32;
    unsigned short* pmat = srcp + (size_t)nbin * BCAP;
    unsigned short* lmat = pmat + (size_t)nblk_e * NBIN_PAD;
    float* W2pack = (float*)(lmat + (size_t)nblk_e * NBIN_PAD);
    int2* pr2 = (int2*)(W2pack + 1024);

    // No memset needed: pmat/lmat fully written, pads explicitly written,
    // dummy quarter-rows zeroed by the weight block.
    sort_pack_cast<<<nblk_e + 1 + CAST_B, 256, 0, stream>>>(
        eidx, ef, rec_c, pmat, lmat, n_edges, nblk_e, n_nodes,
        nf, nfbq, W, b, We, be, Wpack, W2pack);
    fine_rank<<<nbin, 512, 0, stream>>>(rec_c, pmat, lmat, rec, srcp, pr2,
                                        n_nodes, nblk_e);
    aggregate_bf16<<<4 * nbn, 256, 0, stream>>>(nfbq, rec, srcp, pr2, Sq, E8,
                                                n_nodes, nbn);
    gemm_mfma<<<(n_nodes + 63) / 64, 256, 0, stream>>>(Sq, E8, Wpack, W2pack, out, n_nodes);
}

// Round 9
// 210.842 us; speedup vs baseline: 1.1021x; 1.1021x over previous
//
#include <hip/hip_runtime.h>
#include <hip/hip_bf16.h>
#include <stdint.h>

#define IN_F 128
#define EDGE_F 6
#define TILE_E 4096      // per-block sort tile (block-local)
#define NBIN_PAD 256     // coarse bins = dst>>8 (n_nodes <= 65536; N=50000 -> 196 used)
#define BCAP 8192        // padded records per bucket (POW2; ~60 sigma margin)
#define BCAP_SH 13       // log2(BCAP)
#define IDXN 8192        // fine_rank LDS index capacity
#define CAST_B 400       // dedicated cast blocks riding in the K1 grid

using bf16x8 = __attribute__((ext_vector_type(8))) short;  // 8 bf16 = 4 VGPRs
using f32x4  = __attribute__((ext_vector_type(4))) float;

__device__ __forceinline__ float bf2f(unsigned short u) {
    return __uint_as_float(((unsigned int)u) << 16);
}
__device__ __forceinline__ unsigned short f2bfbits(float f) {
    __hip_bfloat16 h = __float2bfloat16(f);  // RNE
    return *reinterpret_cast<unsigned short*>(&h);
}
__device__ __forceinline__ unsigned int packbf(float a, float b) {
    return ((unsigned int)f2bfbits(b) << 16) | (unsigned int)f2bfbits(a);
}

// ---- K1: block-LOCAL counting sort + inline pack + QUARTER-MAJOR nf cast ----
// Sort blocks: LDS hist of 256 coarse bins, local scan, scatter packed records
// bin-grouped within their own 64KB segment. No cross-block coordination.
// Cast blocks write nfbq QUARTER-MAJOR: nfbq[q][(N+1)][32 feats] -- four 3.2MB
// tables, each L2-resident per XCD during the aggregate's per-quarter pass.
// R9: cast's integer division removed (outer q loop, shifts only).
__global__ __launch_bounds__(256) void sort_pack_cast(
        const int* __restrict__ eidx, const float* __restrict__ ef,
        uint4* __restrict__ rec_c, unsigned short* __restrict__ pmat,
        unsigned short* __restrict__ lmat,
        int n_edges, int nblk_e, int n_nodes,
        const float* __restrict__ nf, unsigned short* __restrict__ nfbq,
        const float* __restrict__ W, const float* __restrict__ b,
        const float* __restrict__ We, const float* __restrict__ be,
        unsigned short* __restrict__ Wpack, float* __restrict__ W2pack) {
    const int tid = threadIdx.x;
    const int blk = blockIdx.x;
    const size_t qstr = (size_t)(n_nodes + 1) * 32;   // ushorts per quarter table
    __shared__ unsigned int qxs[TILE_E];   // 16 KB: packed src|dst<<16
    __shared__ int hist[NBIN_PAD];
    __shared__ int cur[NBIN_PAD];

    if (blk < nblk_e) {
        hist[tid] = 0;
        __syncthreads();
        const int e0 = blk * TILE_E;
        const int lim = min(TILE_E, n_edges - e0);
        // pass A: stage qx in LDS + LDS hist (eidx read ONCE)
        for (int i = tid; i < lim; i += 256) {
            const int2 pr = reinterpret_cast<const int2*>(eidx)[e0 + i];  // (src,dst)
            const unsigned int q = (unsigned int)pr.x | ((unsigned int)pr.y << 16);
            qxs[i] = q;
            atomicAdd(&hist[q >> 24], 1);          // q>>24 == dst>>8
        }
        __syncthreads();
        const int own = hist[tid];
        for (int off = 1; off < 256; off <<= 1) {  // inclusive scan of bin counts
            int t2 = (tid >= off) ? hist[tid - off] : 0;
            __syncthreads();
            hist[tid] += t2;
            __syncthreads();
        }
        const int excl = hist[tid] - own;          // local bin offset
        pmat[(size_t)blk * NBIN_PAD + tid] = (unsigned short)own;
        lmat[(size_t)blk * NBIN_PAD + tid] = (unsigned short)excl;
        cur[tid] = excl;
        __syncthreads();
        // pass B: read ef (coalesced), pack 16B record, scatter into OWN segment
        uint4* seg = rec_c + (size_t)blk * TILE_E;
        for (int i = tid; i < lim; i += 256) {
            const unsigned int q = qxs[i];
            const float2* efs = reinterpret_cast<const float2*>(ef + (size_t)(e0 + i) * EDGE_F);
            const float2 f0 = efs[0], f1 = efs[1], f2 = efs[2];
            uint4 r;
            r.x = q;
            r.y = packbf(f0.x, f0.y);
            r.z = packbf(f1.x, f1.y);
            r.w = packbf(f2.x, f2.y);
            const int pos = atomicAdd(&cur[q >> 24], 1);
            seg[pos] = r;                          // 64KB window, bin-grouped
        }
    } else if (blk == nblk_e) {
        // Wpack: idx=((kb*8+ft)*64+lane)*8+j -> bf16(W[kb*32+(lane>>4)*8+j][ft*16+(lane&15)])
        for (int idx = tid; idx < 16384; idx += 256) {
            int j = idx & 7, lane = (idx >> 3) & 63, ft = (idx >> 9) & 7, kb = idx >> 12;
            int k = kb * 32 + (lane >> 4) * 8 + j;
            int f = ft * 16 + (lane & 15);
            Wpack[idx] = f2bfbits(W[k * 128 + f]);
        }
        for (int idx = tid; idx < 1024; idx += 256) {
            int j = idx >> 7, f = idx & 127;
            float w = 0.f;
            if (j < 6)       w = We[j * 128 + f];
            else if (j == 6) w = b[f] + be[f];
            W2pack[idx] = w;
        }
        // dummy node row (index n_nodes) in EACH quarter table: zero 64B.
        if (tid < 16) {
            const int q = tid >> 2, sub = tid & 3;
            uint4 z; z.x = z.y = z.z = z.w = 0u;
            *reinterpret_cast<uint4*>(nfbq + (size_t)q * qstr +
                                      (size_t)n_nodes * 32 + sub * 8) = z;
        }
    } else {
        // cast: nf fp32 -> bf16, quarter-major. Unit = 16B out (8 feats).
        // Outer q loop -> inner index math is shifts only (no division).
        const int cb = blk - nblk_e - 1;
        const int ncb = gridDim.x - nblk_e - 1;
        const int per_q = n_nodes * 4;
        for (int q = 0; q < 4; ++q) {
            unsigned short* dq = nfbq + (size_t)q * qstr;
            const float* sq = nf + q * 32;
            for (int i = cb * 256 + tid; i < per_q; i += ncb * 256) {
                const int node = i >> 2, sub = i & 3;
                const float4 lo = *reinterpret_cast<const float4*>(
                    sq + (size_t)node * IN_F + sub * 8);
                const float4 hi = *reinterpret_cast<const float4*>(
                    sq + (size_t)node * IN_F + sub * 8 + 4);
                uint4 o;
                o.x = packbf(lo.x, lo.y); o.y = packbf(lo.z, lo.w);
                o.z = packbf(hi.x, hi.y); o.w = packbf(hi.z, hi.w);
                *reinterpret_cast<uint4*>(dq + (size_t)node * 32 + sub * 8) = o;
            }
        }
    }
}

// ---- K2: FLAT-PARALLEL bucket assembly + fine sort -> PADDED rec + srcp + pr2 ----
// 512 threads/bucket; run-length scan + 8-step binary search resolves every
// record index; 4-deep independent batches both passes; indices cached in
// 32KB LDS between passes (R7 win). Writes srcp[] (ranked src, 2B/edge) so
// the aggregate's quarter passes never chase the 16B records for addresses.
// Pads (src=n_nodes -> zero rows) keep every dst run a multiple of 8.
__global__ __launch_bounds__(512) void fine_rank(
        const uint4* __restrict__ rec_c, const unsigned short* __restrict__ pmat,
        const unsigned short* __restrict__ lmat,
        uint4* __restrict__ rec, unsigned short* __restrict__ srcp,
        int2* __restrict__ pr2, int n_nodes, int nblk_e) {
    const int tid = threadIdx.x;
    const int c = blockIdx.x;
    __shared__ int rstart[NBIN_PAD + 1];
    __shared__ int rbaseg[NBIN_PAD];
    __shared__ int fcnt[256];
    __shared__ int fpos[256];
    __shared__ int idxl[IDXN];             // 32 KB: linearized global record idx

    if (tid < 256) {
        const bool r = (tid < nblk_e);
        fcnt[tid] = r ? pmat[(size_t)tid * NBIN_PAD + c] : 0;
        rbaseg[tid] = tid * TILE_E + (r ? (int)lmat[(size_t)tid * NBIN_PAD + c] : 0);
    }
    __syncthreads();
    for (int off = 1; off < 256; off <<= 1) {
        int v = 0;
        if (tid < 256 && tid >= off) v = fcnt[tid - off];
        __syncthreads();
        if (tid < 256) fcnt[tid] += v;
        __syncthreads();
    }
    if (tid < 256) rstart[tid + 1] = fcnt[tid];
    if (tid == 0) rstart[0] = 0;
    __syncthreads();
    int sz = rstart[256];
    if (sz > IDXN) sz = IDXN;                   // guard only
    __syncthreads();
    if (tid < 256) fcnt[tid] = 0;
    __syncthreads();
    // pass 1: resolve indices (binary search), cache, dst histogram
    for (int base = 0; base < sz; base += 2048) {
        int ii[4], g[4];
        unsigned int qx[4];
#pragma unroll
        for (int u = 0; u < 4; ++u) ii[u] = base + u * 512 + tid;
#pragma unroll
        for (int u = 0; u < 4; ++u) {
            if (ii[u] < sz) {
                int lo = 0, hi = 255;
                while (lo < hi) {
                    const int mid = (lo + hi + 1) >> 1;
                    if (rstart[mid] <= ii[u]) lo = mid; else hi = mid - 1;
                }
                g[u] = rbaseg[lo] + (ii[u] - rstart[lo]);
                idxl[ii[u]] = g[u];
            }
        }
#pragma unroll
        for (int u = 0; u < 4; ++u)
            if (ii[u] < sz)
                qx[u] = reinterpret_cast<const unsigned int*>(rec_c)[(size_t)g[u] * 4];
#pragma unroll
        for (int u = 0; u < 4; ++u)
            if (ii[u] < sz) atomicAdd(&fcnt[(qx[u] >> 16) & 255], 1);
    }
    __syncthreads();
    int own = 0, ownp = 0, pexcl = 0;
    if (tid < 256) { own = fcnt[tid]; ownp = (own + 7) & ~7; fcnt[tid] = ownp; }
    __syncthreads();
    for (int off = 1; off < 256; off <<= 1) {
        int v = 0;
        if (tid < 256 && tid >= off) v = fcnt[tid - off];
        __syncthreads();
        if (tid < 256) fcnt[tid] += v;
        __syncthreads();
    }
    const size_t obase = (size_t)c * BCAP;
    if (tid < 256) {
        pexcl = fcnt[tid] - ownp;
        fpos[tid] = pexcl;
        const int n = c * 256 + tid;
        if (n < n_nodes) {
            int2 pr; pr.x = (int)(obase + pexcl); pr.y = own;
            pr2[n] = pr;
        }
    }
    __syncthreads();
    // pass 2: ranked scatter of records + srcp via cached indices
    for (int base = 0; base < sz; base += 2048) {
        int ii[4];
        uint4 q[4];
#pragma unroll
        for (int u = 0; u < 4; ++u) ii[u] = base + u * 512 + tid;
#pragma unroll
        for (int u = 0; u < 4; ++u)
            if (ii[u] < sz) q[u] = rec_c[idxl[ii[u]]];
#pragma unroll
        for (int u = 0; u < 4; ++u) {
            if (ii[u] < sz) {
                const int r = atomicAdd(&fpos[(q[u].x >> 16) & 255], 1);
                if (r < BCAP) {
                    rec[obase + r] = q[u];
                    srcp[obase + r] = (unsigned short)(q[u].x & 0xFFFFu);
                }
            }
        }
    }
    // pad fill: thread tid owns dst tid's <=7 dummy slots
    if (tid < 256) {
        uint4 dmy; dmy.x = (unsigned int)n_nodes; dmy.y = dmy.z = dmy.w = 0u;
        for (int j = own; j < ownp && pexcl + j < BCAP; ++j) {
            rec[obase + pexcl + j] = dmy;
            srcp[obase + pexcl + j] = (unsigned short)n_nodes;
        }
    }
}

// ---- K3: aggregate, quarter-split gather with RESTORED 4-deep ILP. ----
// R8 post-mortem: quarter-split cut FETCH 210->77MB (L2 residency works) but
// serial srcp->gather chains (1 in flight) + 64-lane-redundant e-sums doubled
// time. R9 fix: per iteration, ONE coalesced srcp read covers 32 edges
// (lane&31), shfl-distributed; FOUR independent 64B-row gathers issued
// back-to-back; invalid batches address-clamped + masked by a wave-uniform
// 0/1 fmac multiplier (no divergence). Pass-0 edge-feature sums distributed
// across lanes (1 dword load + 1 fmac per lane per batch, folded at end).
__global__ __launch_bounds__(256) void aggregate_bf16(
        const unsigned short* __restrict__ nfbq, const uint4* __restrict__ rec,
        const unsigned short* __restrict__ srcp, const int2* __restrict__ pr2,
        unsigned short* __restrict__ Sq, unsigned short* __restrict__ E8,
        int n_nodes, int nbn) {
    const int lane = threadIdx.x & 63;
    const int wv = __builtin_amdgcn_readfirstlane(threadIdx.x >> 6);
    const int pass = blockIdx.x / nbn;
    const int bi = blockIdx.x - pass * nbn;
    const int n = bi * 4 + wv;
    if (n >= n_nodes) return;
    const size_t qstr = (size_t)(n_nodes + 1) * 32;
    const unsigned short* tab = nfbq + (size_t)pass * qstr;
    const int2 pr = pr2[n];
    const int deg = pr.y;
    const int nb = (deg + 7) >> 3;             // 8-record batches (padded)
    const int es = lane >> 3;                  // edge slot 0..7
    const int fl = lane & 7;                   // feat slot (4 bf16 = 8B)
    const int c_end = ((pr.x >> BCAP_SH) + 1) << BCAP_SH;  // bucket bound
    float b0 = 0.f, b1 = 0.f, b2 = 0.f, b3 = 0.f;
    float eacc = 0.f;
    const float emaskf = (fl < 6) ? 1.f : 0.f;
    const int wsel = (fl >> 1) > 2 ? 2 : (fl >> 1);   // feat word within record
    const unsigned int hsh = (unsigned int)(fl & 1) * 16;
    for (int bb = 0; bb < nb; bb += 4) {
        const int i = pr.x + bb * 8;
        int sidx = i + (lane & 31);
        sidx = min(sidx, c_end - 1);
        const int sl = (int)srcp[sidx];        // ONE coalesced 2B/lane read
        float m[4];
        int sg[4];
#pragma unroll
        for (int g = 0; g < 4; ++g) {
            m[g] = (bb + g < nb) ? 1.f : 0.f;  // wave-uniform mask
            const int s = __shfl(sl, g * 8 + es, 64);
            sg[g] = min(s, n_nodes);           // clamp garbage to dummy row
        }
        uint2 u[4];
#pragma unroll
        for (int g = 0; g < 4; ++g)            // 4 independent 64B-row gathers
            u[g] = *reinterpret_cast<const uint2*>(tab + (size_t)sg[g] * 32 + fl * 4);
        if (pass == 0) {                       // distributed edge-feature sums
            unsigned int w[4];
#pragma unroll
            for (int g = 0; g < 4; ++g) {
                const int ei = min(i + g * 8 + es, c_end - 1);
                w[g] = *reinterpret_cast<const unsigned int*>(
                    reinterpret_cast<const char*>(rec) + (size_t)ei * 16 + 4 + wsel * 4);
            }
#pragma unroll
            for (int g = 0; g < 4; ++g)
                eacc += (m[g] * emaskf) * bf2f((unsigned short)(w[g] >> hsh));
        }
#pragma unroll
        for (int g = 0; g < 4; ++g) {
            b0 += m[g] * bf2f((unsigned short)u[g].x);
            b1 += m[g] * bf2f((unsigned short)(u[g].x >> 16));
            b2 += m[g] * bf2f((unsigned short)u[g].y);
            b3 += m[g] * bf2f((unsigned short)(u[g].y >> 16));
        }
    }
    // fold node-feat partials across edge-slot groups (lane bits 3,4,5)
    b0 += __shfl_xor(b0, 8, 64);  b1 += __shfl_xor(b1, 8, 64);
    b2 += __shfl_xor(b2, 8, 64);  b3 += __shfl_xor(b3, 8, 64);
    b0 += __shfl_xor(b0, 16, 64); b1 += __shfl_xor(b1, 16, 64);
    b2 += __shfl_xor(b2, 16, 64); b3 += __shfl_xor(b3, 16, 64);
    b0 += __shfl_xor(b0, 32, 64); b1 += __shfl_xor(b1, 32, 64);
    b2 += __shfl_xor(b2, 32, 64); b3 += __shfl_xor(b3, 32, 64);
    if (es == 0) {                             // lanes 0..7 write the 64B quarter-row
        uint2 o;
        o.x = packbf(b0, b1);
        o.y = packbf(b2, b3);
        *reinterpret_cast<uint2*>(Sq + (size_t)pass * n_nodes * 32 +
                                  (size_t)n * 32 + fl * 4) = o;
    }
    if (pass == 0) {
        eacc += __shfl_xor(eacc, 8, 64);
        eacc += __shfl_xor(eacc, 16, 64);
        eacc += __shfl_xor(eacc, 32, 64);      // lane j now holds feat-j sum
        const float e0 = __shfl(eacc, 0, 64);
        const float e1 = __shfl(eacc, 1, 64);
        const float e2 = __shfl(eacc, 2, 64);
        const float e3 = __shfl(eacc, 3, 64);
        const float e4 = __shfl(eacc, 4, 64);
        const float e5 = __shfl(eacc, 5, 64);
        if (lane == 0) {
            uint4 q;
            q.x = packbf(e0, e1);
            q.y = packbf(e2, e3);
            q.z = packbf(e4, e5);
            q.w = packbf((float)deg, 0.f);      // deg exact in bf16 (small)
            *reinterpret_cast<uint4*>(E8 + (size_t)n * 8) = q;
        }
    }
}

// ---- K4: MFMA GEMM  out = relu( S @ W + E-term ), S quarter-major ----
// a[kb] comes from quarter table kb (exactly the MFMA K-block) -- still a
// 16B/lane fully-coalesced load. Coalesced LDS-staged epilogue (R7 win).
__global__ __launch_bounds__(256) void gemm_mfma(
        const unsigned short* __restrict__ Sq, const unsigned short* __restrict__ E8,
        const unsigned short* __restrict__ Wpack, const float* __restrict__ W2pack,
        float* __restrict__ out, int n_nodes) {
    __shared__ __align__(16) short Wl[16384];   // 32 KB: B-fragments, then out-stage
    __shared__ float W2l[1024];                 // 4 KB
    const int tid = threadIdx.x;
    for (int i = tid; i < 2048; i += 256)
        reinterpret_cast<uint4*>(Wl)[i] = reinterpret_cast<const uint4*>(Wpack)[i];
    for (int i = tid; i < 1024; i += 256) W2l[i] = W2pack[i];

    const int wv = tid >> 6, lane = tid & 63;
    const int m = lane & 15, quad = lane >> 4;
    const int n0 = blockIdx.x * 64 + wv * 16;

    const int arow = min(n0 + m, n_nodes - 1);
    bf16x8 a[4];
#pragma unroll
    for (int kb = 0; kb < 4; ++kb)
        a[kb] = *reinterpret_cast<const bf16x8*>(
            Sq + (size_t)kb * n_nodes * 32 + (size_t)arow * 32 + quad * 8);

    __syncthreads();

    f32x4 acc[8];
#pragma unroll
    for (int ft = 0; ft < 8; ++ft) acc[ft] = (f32x4){0.f, 0.f, 0.f, 0.f};

#pragma unroll
    for (int kb = 0; kb < 4; ++kb) {
#pragma unroll
        for (int ft = 0; ft < 8; ++ft) {
            const bf16x8 bfrag =
                reinterpret_cast<const bf16x8*>(Wl)[(kb * 8 + ft) * 64 + lane];
            acc[ft] = __builtin_amdgcn_mfma_f32_16x16x32_bf16(a[kb], bfrag, acc[ft], 0, 0, 0);
        }
    }

    // Epilogue. C/D layout: col=lane&15, row=quad*4+reg.
    float e[4][7];
#pragma unroll
    for (int r = 0; r < 4; ++r) {
        const int n = min(n0 + quad * 4 + r, n_nodes - 1);
        const uint4 q = *reinterpret_cast<const uint4*>(E8 + (size_t)n * 8);
        e[r][0] = bf2f((unsigned short)q.x); e[r][1] = bf2f((unsigned short)(q.x >> 16));
        e[r][2] = bf2f((unsigned short)q.y); e[r][3] = bf2f((unsigned short)(q.y >> 16));
        e[r][4] = bf2f((unsigned short)q.z); e[r][5] = bf2f((unsigned short)(q.z >> 16));
        e[r][6] = bf2f((unsigned short)q.w);  // deg
    }
    __syncthreads();                            // Wl B-fragment reads complete
    float* So = reinterpret_cast<float*>(Wl);   // 64 rows x 128 f32 = 32 KB
#pragma unroll
    for (int ft = 0; ft < 8; ++ft) {
        const int f = ft * 16 + m;
        float w2[7];
#pragma unroll
        for (int j = 0; j < 7; ++j) w2[j] = W2l[j * 128 + f];
#pragma unroll
        for (int r = 0; r < 4; ++r) {
            float v = acc[ft][r];
#pragma unroll
            for (int j = 0; j < 7; ++j) v += e[r][j] * w2[j];
            So[(wv * 16 + quad * 4 + r) * 128 + f] = fmaxf(v, 0.f);
        }
    }
    __syncthreads();
    const size_t nb0 = (size_t)blockIdx.x * 64;
    for (int i = tid; i < 2048; i += 256) {     // 16B/lane, fully coalesced
        const int row = i >> 5;
        if (nb0 + row < (size_t)n_nodes)
            reinterpret_cast<uint4*>(out)[(nb0 + row) * 32 + (i & 31)] =
                reinterpret_cast<const uint4*>(So)[i];
    }
}

extern "C" void kernel_launch(void* const* d_in, const int* in_sizes, int n_in,
                              void* d_out, int out_size, void* d_ws, size_t ws_size,
                              hipStream_t stream) {
    const float* nf = (const float*)d_in[0];  // fp32 (N,128)
    const int* eidx = (const int*)d_in[1];    // int32 (E,2)
    const float* ef = (const float*)d_in[2];  // fp32 (E,6)
    const float* W  = (const float*)d_in[3];  // fp32 (128,128)
    const float* b  = (const float*)d_in[4];  // fp32 (128,)
    const float* We = (const float*)d_in[5];  // fp32 (6,128)
    const float* be = (const float*)d_in[6];  // fp32 (128,)
    float* out = (float*)d_out;               // fp32 (N,128)

    const int n_nodes = in_sizes[0] / IN_F;
    const int n_edges = in_sizes[1] / 2;

    const int nblk_e = (n_edges + TILE_E - 1) / TILE_E;   // 196 sort blocks (<=256 req'd)
    const int nbin = (n_nodes + 255) >> 8;                // 196 fine buckets
    const int nbn = (n_nodes + 3) / 4;                    // aggregate blocks per pass

    // ws (~70 MB), all 16B-aligned section sizes:
    // rec (nbin*BCAP uint4) | rec_c (nblk_e*TILE_E uint4) | E8 | Wpack
    //   | Sq (4*N*32 ush, quarter-major) | nfbq (4*(N+1)*32 ush) | srcp
    //   | pmat | lmat | W2pack | pr2
    uint4* rec   = (uint4*)d_ws;
    uint4* rec_c = rec + (size_t)nbin * BCAP;
    unsigned short* E8 = (unsigned short*)(rec_c + (size_t)nblk_e * TILE_E);
    unsigned short* Wpack = E8 + (size_t)n_nodes * 8;
    unsigned short* Sq = Wpack + 16384;
    unsigned short* nfbq = Sq + (size_t)4 * n_nodes * 32;
    unsigned short* srcp = nfbq + (size_t)4 * (n_nodes + 1) * 32;
    unsigned short* pmat = srcp + (size_t)nbin * BCAP;
    unsigned short* lmat = pmat + (size_t)nblk_e * NBIN_PAD;
    float* W2pack = (float*)(lmat + (size_t)nblk_e * NBIN_PAD);
    int2* pr2 = (int2*)(W2pack + 1024);

    // No memset needed: pmat/lmat fully written, pads explicitly written,
    // dummy quarter-rows zeroed by the weight block.
    sort_pack_cast<<<nblk_e + 1 + CAST_B, 256, 0, stream>>>(
        eidx, ef, rec_c, pmat, lmat, n_edges, nblk_e, n_nodes,
        nf, nfbq, W, b, We, be, Wpack, W2pack);
    fine_rank<<<nbin, 512, 0, stream>>>(rec_c, pmat, lmat, rec, srcp, pr2,
                                        n_nodes, nblk_e);
    aggregate_bf16<<<4 * nbn, 256, 0, stream>>>(nfbq, rec, srcp, pr2, Sq, E8,
                                                n_nodes, nbn);
    gemm_mfma<<<(n_nodes + 63) / 64, 256, 0, stream>>>(Sq, E8, Wpack, W2pack, out, n_nodes);
}

// Round 10
// 177.693 us; speedup vs baseline: 1.3077x; 1.1866x over previous
//
#include <hip/hip_runtime.h>
#include <hip/hip_bf16.h>
#include <stdint.h>

#define IN_F 128
#define EDGE_F 6
#define TILE_E 4096      // per-block sort tile (block-local, no cross-block mapping needed)
#define NBIN_PAD 256     // coarse bins = dst>>8 (n_nodes <= 65536; N=50000 -> 196 used)
#define BCAP 8192        // padded records per bucket (~60 sigma margin)
#define IDXN 8192        // fine_rank LDS index capacity
#define CAST_B 400       // dedicated cast blocks riding in the K1 grid

using bf16x8 = __attribute__((ext_vector_type(8))) short;  // 8 bf16 = 4 VGPRs
using f32x4  = __attribute__((ext_vector_type(4))) float;

__device__ __forceinline__ float bf2f(unsigned short u) {
    return __uint_as_float(((unsigned int)u) << 16);
}
__device__ __forceinline__ unsigned short f2bfbits(float f) {
    __hip_bfloat16 h = __float2bfloat16(f);  // RNE
    return *reinterpret_cast<unsigned short*>(&h);
}
__device__ __forceinline__ unsigned int packbf(float a, float b) {
    return ((unsigned int)f2bfbits(b) << 16) | (unsigned int)f2bfbits(a);
}

// ---- K1: block-LOCAL counting sort + inline pack + nf cast + weight pack ----
// Each sort block owns tile blk*TILE_E and its own output segment: LDS hist
// of 256 coarse bins, local scan, scatter packed records bin-grouped within
// its 64KB segment. No cross-block coordination. Cast blocks and the
// weight-pack block ride in the same grid (independent work).
// NOTE (R8/R9 post-mortem): quarter-major nfb layouts cut aggregate FETCH
// 210->72MB but turned it VALU-bound (41us+ of per-pass overhead) -- net
// worse than this linear layout. Keep linear.
__global__ __launch_bounds__(256) void sort_pack_cast(
        const int* __restrict__ eidx, const float* __restrict__ ef,
        uint4* __restrict__ rec_c, unsigned short* __restrict__ pmat,
        unsigned short* __restrict__ lmat,
        int n_edges, int nblk_e, int n_cast, int n_nodes,
        const float* __restrict__ nf, unsigned short* __restrict__ nfb,
        const float* __restrict__ W, const float* __restrict__ b,
        const float* __restrict__ We, const float* __restrict__ be,
        unsigned short* __restrict__ Wpack, float* __restrict__ W2pack) {
    const int tid = threadIdx.x;
    const int blk = blockIdx.x;
    __shared__ unsigned int qxs[TILE_E];   // 16 KB: packed src|dst<<16, staged once
    __shared__ int hist[NBIN_PAD];         // counts -> inclusive scan
    __shared__ int cur[NBIN_PAD];          // scatter cursors

    if (blk < nblk_e) {
        hist[tid] = 0;
        __syncthreads();
        const int e0 = blk * TILE_E;
        const int lim = min(TILE_E, n_edges - e0);
        // pass A: stage qx in LDS + LDS hist (eidx read ONCE)
        for (int i = tid; i < lim; i += 256) {
            const int2 pr = reinterpret_cast<const int2*>(eidx)[e0 + i];  // (src,dst)
            const unsigned int q = (unsigned int)pr.x | ((unsigned int)pr.y << 16);
            qxs[i] = q;
            atomicAdd(&hist[q >> 24], 1);          // q>>24 == dst>>8
        }
        __syncthreads();
        const int own = hist[tid];
        for (int off = 1; off < 256; off <<= 1) {  // inclusive scan of bin counts
            int t2 = (tid >= off) ? hist[tid - off] : 0;
            __syncthreads();
            hist[tid] += t2;
            __syncthreads();
        }
        const int excl = hist[tid] - own;          // local bin offset
        pmat[(size_t)blk * NBIN_PAD + tid] = (unsigned short)own;
        lmat[(size_t)blk * NBIN_PAD + tid] = (unsigned short)excl;
        cur[tid] = excl;
        __syncthreads();
        // pass B: read ef (coalesced), pack 16B record, scatter into OWN segment
        uint4* seg = rec_c + (size_t)blk * TILE_E;
        for (int i = tid; i < lim; i += 256) {
            const unsigned int q = qxs[i];
            const float2* efs = reinterpret_cast<const float2*>(ef + (size_t)(e0 + i) * EDGE_F);
            const float2 f0 = efs[0], f1 = efs[1], f2 = efs[2];
            uint4 r;
            r.x = q;
            r.y = packbf(f0.x, f0.y);
            r.z = packbf(f1.x, f1.y);
            r.w = packbf(f2.x, f2.y);
            const int pos = atomicAdd(&cur[q >> 24], 1);
            seg[pos] = r;                          // 64KB window, bin-grouped
        }
    } else if (blk == nblk_e) {
        // Wpack: idx=((kb*8+ft)*64+lane)*8+j -> bf16(W[kb*32+(lane>>4)*8+j][ft*16+(lane&15)])
        for (int idx = tid; idx < 16384; idx += 256) {
            int j = idx & 7, lane = (idx >> 3) & 63, ft = (idx >> 9) & 7, kb = idx >> 12;
            int k = kb * 32 + (lane >> 4) * 8 + j;
            int f = ft * 16 + (lane & 15);
            Wpack[idx] = f2bfbits(W[k * 128 + f]);
        }
        for (int idx = tid; idx < 1024; idx += 256) {
            int j = idx >> 7, f = idx & 127;
            float w = 0.f;
            if (j < 6)       w = We[j * 128 + f];
            else if (j == 6) w = b[f] + be[f];
            W2pack[idx] = w;
        }
        // dummy node row (index n_nodes): zero. Pad records gather from here.
        if (tid < 16) {
            uint4 z; z.x = z.y = z.z = z.w = 0u;
            reinterpret_cast<uint4*>(nfb + (size_t)n_nodes * IN_F)[tid] = z;
        }
    } else {
        // cast block: nf -> bf16, vectorized (uint4 in / uint4 out)
        const int cb = blk - nblk_e - 1;
        const int ncb = gridDim.x - nblk_e - 1;
        for (int i = cb * 256 + tid; i < n_cast; i += ncb * 256) {
            const float4 lo = reinterpret_cast<const float4*>(nf)[2 * i];
            const float4 hi = reinterpret_cast<const float4*>(nf)[2 * i + 1];
            uint4 o;
            o.x = packbf(lo.x, lo.y); o.y = packbf(lo.z, lo.w);
            o.z = packbf(hi.x, hi.y); o.w = packbf(hi.z, hi.w);
            reinterpret_cast<uint4*>(nfb)[i] = o;
        }
    }
}

// ---- K2: FLAT-PARALLEL bucket assembly + fine sort -> PADDED CSR rec + pr2 ----
// 512 threads/bucket; scan the 196 run lengths; every record index resolved
// by an 8-step LDS binary search; records processed in flat 4-deep
// independent batches (pipelined loads) in both passes; linearized record
// indices cached in 32KB LDS between passes (R7: +17us win over serial-run
// walk). Output at static base c*BCAP; runs padded to a multiple of 8 with
// dummy records (src=n_nodes -> zero row).
__global__ __launch_bounds__(512) void fine_rank(
        const uint4* __restrict__ rec_c, const unsigned short* __restrict__ pmat,
        const unsigned short* __restrict__ lmat,
        uint4* __restrict__ rec, int2* __restrict__ pr2,
        int n_nodes, int nblk_e) {
    const int tid = threadIdx.x;
    const int c = blockIdx.x;
    __shared__ int rstart[NBIN_PAD + 1];   // run-start prefix within bucket
    __shared__ int rbaseg[NBIN_PAD];       // global record idx of each run start
    __shared__ int fcnt[256];              // scratch: run scan, then dst hist/scan
    __shared__ int fpos[256];
    __shared__ int idxl[IDXN];             // 32 KB: linearized global record idx

    if (tid < 256) {
        const bool r = (tid < nblk_e);
        fcnt[tid] = r ? pmat[(size_t)tid * NBIN_PAD + c] : 0;
        rbaseg[tid] = tid * TILE_E + (r ? (int)lmat[(size_t)tid * NBIN_PAD + c] : 0);
    }
    __syncthreads();
    for (int off = 1; off < 256; off <<= 1) {   // inclusive scan of run lengths
        int v = 0;
        if (tid < 256 && tid >= off) v = fcnt[tid - off];
        __syncthreads();
        if (tid < 256) fcnt[tid] += v;
        __syncthreads();
    }
    if (tid < 256) rstart[tid + 1] = fcnt[tid];
    if (tid == 0) rstart[0] = 0;
    __syncthreads();
    int sz = rstart[256];
    if (sz > IDXN) sz = IDXN;                   // ~64-sigma impossible; guard only
    __syncthreads();
    if (tid < 256) fcnt[tid] = 0;
    __syncthreads();
    // pass 1: resolve indices (binary search), cache in LDS, dst histogram.
    for (int base = 0; base < sz; base += 2048) {
        int ii[4], g[4];
        unsigned int qx[4];
#pragma unroll
        for (int u = 0; u < 4; ++u) ii[u] = base + u * 512 + tid;
#pragma unroll
        for (int u = 0; u < 4; ++u) {
            if (ii[u] < sz) {
                int lo = 0, hi = 255;
                while (lo < hi) {               // max j with rstart[j] <= i
                    const int mid = (lo + hi + 1) >> 1;
                    if (rstart[mid] <= ii[u]) lo = mid; else hi = mid - 1;
                }
                g[u] = rbaseg[lo] + (ii[u] - rstart[lo]);
                idxl[ii[u]] = g[u];
            }
        }
#pragma unroll
        for (int u = 0; u < 4; ++u)             // 4 independent loads in flight
            if (ii[u] < sz)
                qx[u] = reinterpret_cast<const unsigned int*>(rec_c)[(size_t)g[u] * 4];
#pragma unroll
        for (int u = 0; u < 4; ++u)
            if (ii[u] < sz) atomicAdd(&fcnt[(qx[u] >> 16) & 255], 1);
    }
    __syncthreads();
    int own = 0, ownp = 0, pexcl = 0;
    if (tid < 256) { own = fcnt[tid]; ownp = (own + 7) & ~7; fcnt[tid] = ownp; }
    __syncthreads();
    for (int off = 1; off < 256; off <<= 1) {   // inclusive scan of padded lengths
        int v = 0;
        if (tid < 256 && tid >= off) v = fcnt[tid - off];
        __syncthreads();
        if (tid < 256) fcnt[tid] += v;
        __syncthreads();
    }
    const size_t obase = (size_t)c * BCAP;
    if (tid < 256) {
        pexcl = fcnt[tid] - ownp;
        fpos[tid] = pexcl;
        const int n = c * 256 + tid;
        if (n < n_nodes) {
            int2 pr; pr.x = (int)(obase + pexcl); pr.y = own;
            pr2[n] = pr;
        }
    }
    __syncthreads();
    // pass 2: ranked scatter via cached indices (4-deep batches).
    for (int base = 0; base < sz; base += 2048) {
        int ii[4];
        uint4 q[4];
#pragma unroll
        for (int u = 0; u < 4; ++u) ii[u] = base + u * 512 + tid;
#pragma unroll
        for (int u = 0; u < 4; ++u)
            if (ii[u] < sz) q[u] = rec_c[idxl[ii[u]]];
#pragma unroll
        for (int u = 0; u < 4; ++u) {
            if (ii[u] < sz) {
                const int r = atomicAdd(&fpos[(q[u].x >> 16) & 255], 1);
                if (r < BCAP) rec[obase + r] = q[u];
            }
        }
    }
    // pad fill: thread tid owns dst tid's <=7 dummy slots
    if (tid < 256) {
        uint4 dmy; dmy.x = (unsigned int)n_nodes; dmy.y = dmy.z = dmy.w = 0u;
        for (int j = own; j < ownp && pexcl + j < BCAP; ++j)
            rec[obase + pexcl + j] = dmy;
    }
}

// ---- K3: aggregate. One wave per dst; half-wave pair gather (8B/lane). ----
// rec[i] loads are wave-uniform -> SGPRs. Every dst run is a multiple of 8
// records; each batch issues 4 dwordx2 gathers covering 8 edges. The gather
// is at the LLC random-256B-row byte-throughput ceiling (~5 TB/s effective):
// R2 concurrency scaling, R4 pad-null, R5 pair-null all agree, and the R8/R9
// quarter-split (L2-resident tables, FETCH 210->72MB) went VALU-bound at
// 61us -- strictly worse. This structure is the measured optimum. Do NOT
// fuse with the MFMA gemm (R12).
__global__ __launch_bounds__(256) void aggregate_bf16(
        const unsigned short* __restrict__ nfb, const uint4* __restrict__ rec,
        const int2* __restrict__ pr2, unsigned short* __restrict__ S,
        unsigned short* __restrict__ E8, int n_nodes) {
    const int lane = threadIdx.x & 63;
    const int wv = __builtin_amdgcn_readfirstlane(threadIdx.x >> 6);
    const int n = blockIdx.x * 4 + wv;
    if (n >= n_nodes) return;
    const int2 pr = pr2[n];
    const int deg = pr.y;
    const int nb = (deg + 7) >> 3;             // all batches full (padded)
    const int half = lane >> 5;                // 0: edge 2p, 1: edge 2p+1
    const int hl = lane & 31;                  // owns feats 4*hl .. 4*hl+3
    float a0 = 0.f, a1 = 0.f, a2 = 0.f, a3 = 0.f;
    float e0 = 0.f, e1 = 0.f, e2 = 0.f, e3 = 0.f, e4 = 0.f, e5 = 0.f;
    int i = pr.x;
    for (int bb = 0; bb < nb; ++bb, i += 8) {
        uint4 q[8];
#pragma unroll
        for (int j = 0; j < 8; ++j) q[j] = rec[i + j];           // SGPR, wave-uniform
        uint2 u[4];
#pragma unroll
        for (int p = 0; p < 4; ++p) {
            const unsigned int sA = q[2 * p].x & 0xFFFFu;
            const unsigned int sB = q[2 * p + 1].x & 0xFFFFu;
            const unsigned int s = half ? sB : sA;
            u[p] = reinterpret_cast<const uint2*>(nfb + (size_t)s * IN_F)[hl];
        }
#pragma unroll
        for (int p = 0; p < 4; ++p) {
            a0 += bf2f((unsigned short)u[p].x);
            a1 += bf2f((unsigned short)(u[p].x >> 16));
            a2 += bf2f((unsigned short)u[p].y);
            a3 += bf2f((unsigned short)(u[p].y >> 16));
        }
#pragma unroll
        for (int j = 0; j < 8; ++j) {
            e0 += bf2f((unsigned short)q[j].y);
            e1 += bf2f((unsigned short)(q[j].y >> 16));
            e2 += bf2f((unsigned short)q[j].z);
            e3 += bf2f((unsigned short)(q[j].z >> 16));
            e4 += bf2f((unsigned short)q[j].w);
            e5 += bf2f((unsigned short)(q[j].w >> 16));
        }
    }
    // fold the two half-wave partials (feats only; e-sums were whole-wave)
    a0 += __shfl_xor(a0, 32, 64);
    a1 += __shfl_xor(a1, 32, 64);
    a2 += __shfl_xor(a2, 32, 64);
    a3 += __shfl_xor(a3, 32, 64);
    if (half == 0) {
        uint2 o;
        o.x = packbf(a0, a1);
        o.y = packbf(a2, a3);
        reinterpret_cast<uint2*>(S + (size_t)n * IN_F)[hl] = o;   // 256B row, 32 lanes
    }
    if (lane == 0) {
        uint4 q;
        q.x = packbf(e0, e1);
        q.y = packbf(e2, e3);
        q.z = packbf(e4, e5);
        q.w = packbf((float)deg, 0.f);          // deg exact in bf16 (small)
        *reinterpret_cast<uint4*>(E8 + (size_t)n * 8) = q;
    }
}

// ---- K4: MFMA GEMM  out = relu( S[N,128]bf16 @ W[128,128]bf16 + E-term ) ----
// Coalesced epilogue: acc staged into the dead Wl buffer (32KB fp32, reused
// post-MFMA), then streamed out as 16B/lane uint4 (R7 win).
__global__ __launch_bounds__(256) void gemm_mfma(
        const unsigned short* __restrict__ S, const unsigned short* __restrict__ E8,
        const unsigned short* __restrict__ Wpack, const float* __restrict__ W2pack,
        float* __restrict__ out, int n_nodes) {
    __shared__ __align__(16) short Wl[16384];   // 32 KB: B-fragments, then out-stage
    __shared__ float W2l[1024];                 // 4 KB
    const int tid = threadIdx.x;
    for (int i = tid; i < 2048; i += 256)
        reinterpret_cast<uint4*>(Wl)[i] = reinterpret_cast<const uint4*>(Wpack)[i];
    for (int i = tid; i < 1024; i += 256) W2l[i] = W2pack[i];

    const int wv = tid >> 6, lane = tid & 63;
    const int m = lane & 15, quad = lane >> 4;
    const int n0 = blockIdx.x * 64 + wv * 16;

    const int arow = min(n0 + m, n_nodes - 1);
    const unsigned short* ap = S + (size_t)arow * IN_F + quad * 8;
    bf16x8 a[4];
#pragma unroll
    for (int kb = 0; kb < 4; ++kb)
        a[kb] = *reinterpret_cast<const bf16x8*>(ap + kb * 32);

    __syncthreads();

    f32x4 acc[8];
#pragma unroll
    for (int ft = 0; ft < 8; ++ft) acc[ft] = (f32x4){0.f, 0.f, 0.f, 0.f};

#pragma unroll
    for (int kb = 0; kb < 4; ++kb) {
#pragma unroll
        for (int ft = 0; ft < 8; ++ft) {
            const bf16x8 bfrag =
                reinterpret_cast<const bf16x8*>(Wl)[(kb * 8 + ft) * 64 + lane];
            acc[ft] = __builtin_amdgcn_mfma_f32_16x16x32_bf16(a[kb], bfrag, acc[ft], 0, 0, 0);
        }
    }

    // Epilogue. C/D layout: col=lane&15, row=quad*4+reg.
    float e[4][7];
#pragma unroll
    for (int r = 0; r < 4; ++r) {
        const int n = min(n0 + quad * 4 + r, n_nodes - 1);
        const uint4 q = *reinterpret_cast<const uint4*>(E8 + (size_t)n * 8);
        e[r][0] = bf2f((unsigned short)q.x); e[r][1] = bf2f((unsigned short)(q.x >> 16));
        e[r][2] = bf2f((unsigned short)q.y); e[r][3] = bf2f((unsigned short)(q.y >> 16));
        e[r][4] = bf2f((unsigned short)q.z); e[r][5] = bf2f((unsigned short)(q.z >> 16));
        e[r][6] = bf2f((unsigned short)q.w);  // deg
    }
    __syncthreads();                            // Wl B-fragment reads complete
    float* So = reinterpret_cast<float*>(Wl);   // 64 rows x 128 f32 = 32 KB
#pragma unroll
    for (int ft = 0; ft < 8; ++ft) {
        const int f = ft * 16 + m;
        float w2[7];
#pragma unroll
        for (int j = 0; j < 7; ++j) w2[j] = W2l[j * 128 + f];
#pragma unroll
        for (int r = 0; r < 4; ++r) {
            float v = acc[ft][r];
#pragma unroll
            for (int j = 0; j < 7; ++j) v += e[r][j] * w2[j];
            So[(wv * 16 + quad * 4 + r) * 128 + f] = fmaxf(v, 0.f);
        }
    }
    __syncthreads();
    const size_t nb0 = (size_t)blockIdx.x * 64;
    for (int i = tid; i < 2048; i += 256) {     // 16B/lane, fully coalesced
        const int row = i >> 5;
        if (nb0 + row < (size_t)n_nodes)
            reinterpret_cast<uint4*>(out)[(nb0 + row) * 32 + (i & 31)] =
                reinterpret_cast<const uint4*>(So)[i];
    }
}

extern "C" void kernel_launch(void* const* d_in, const int* in_sizes, int n_in,
                              void* d_out, int out_size, void* d_ws, size_t ws_size,
                              hipStream_t stream) {
    const float* nf = (const float*)d_in[0];  // fp32 (N,128)
    const int* eidx = (const int*)d_in[1];    // int32 (E,2)
    const float* ef = (const float*)d_in[2];  // fp32 (E,6)
    const float* W  = (const float*)d_in[3];  // fp32 (128,128)
    const float* b  = (const float*)d_in[4];  // fp32 (128,)
    const float* We = (const float*)d_in[5];  // fp32 (6,128)
    const float* be = (const float*)d_in[6];  // fp32 (128,)
    float* out = (float*)d_out;               // fp32 (N,128)

    const int n_nodes = in_sizes[0] / IN_F;
    const int n_edges = in_sizes[1] / 2;

    const int nblk_e = (n_edges + TILE_E - 1) / TILE_E;   // 196 sort blocks (<=256 req'd)
    const int nbin = (n_nodes + 255) >> 8;                // 196 fine buckets
    const int n_cast = n_nodes * (IN_F / 8);

    // ws (~66 MB): rec (nbin*BCAP recs, static padded layout) | rec_c
    //   (nblk_e*TILE_E recs, block-segmented) | S | E8 | Wpack | W2pack
    //   | pr2 | pmat | lmat | nfb ((N+1) rows)
    uint4* rec   = (uint4*)d_ws;
    uint4* rec_c = rec + (size_t)nbin * BCAP;
    unsigned short* S = (unsigned short*)(rec_c + (size_t)nblk_e * TILE_E);
    unsigned short* E8 = S + (size_t)n_nodes * IN_F;
    unsigned short* Wpack = E8 + (size_t)n_nodes * 8;
    float* W2pack = (float*)(Wpack + 16384);
    int2* pr2 = (int2*)(W2pack + 1024);
    unsigned short* pmat = (unsigned short*)(pr2 + n_nodes);
    unsigned short* lmat = pmat + (size_t)nblk_e * NBIN_PAD;
    unsigned short* nfb = lmat + (size_t)nblk_e * NBIN_PAD;

    // No memset needed: pmat/lmat rows fully written by sort blocks, rec/rec_c
    // read only within written bounds, pad records explicitly written.
    sort_pack_cast<<<nblk_e + 1 + CAST_B, 256, 0, stream>>>(
        eidx, ef, rec_c, pmat, lmat, n_edges, nblk_e, n_cast, n_nodes,
        nf, nfb, W, b, We, be, Wpack, W2pack);
    fine_rank<<<nbin, 512, 0, stream>>>(rec_c, pmat, lmat, rec, pr2,
                                        n_nodes, nblk_e);
    aggregate_bf16<<<(n_nodes + 3) / 4, 256, 0, stream>>>(nfb, rec, pr2, S, E8, n_nodes);
    gemm_mfma<<<(n_nodes + 63) / 64, 256, 0, stream>>>(S, E8, Wpack, W2pack, out, n_nodes);
}